// Round 3
// baseline (172.505 us; speedup 1.0000x reference)
//
#include <hip/hip_runtime.h>

#define N 8192
#define CAP 64          // max out-edges per box stored (mean ~10, tail ~25)
#define THR 0.2f

// ---------------- rank: rank[i] = #{j: s_j > s_i or (s_j==s_i and j<i)} ----------------
__global__ __launch_bounds__(256) void rank_kernel(const float* __restrict__ scores,
                                                   unsigned* __restrict__ rank) {
    __shared__ float s[1024];
    const int jbase = blockIdx.y * 1024;
    for (int t = threadIdx.x; t < 1024; t += 256) s[t] = scores[jbase + t];
    __syncthreads();
    const int i = blockIdx.x * 256 + threadIdx.x;
    const float si = scores[i];
    unsigned c = 0;
    #pragma unroll 8
    for (int jj = 0; jj < 1024; ++jj) {
        float sj = s[jj];
        int j = jbase + jj;
        c += (sj > si) || (sj == si && j < i);
    }
    atomicAdd(&rank[i], c);
}

// ---------------- scatter into sorted order ----------------
__global__ __launch_bounds__(256) void scatter_kernel(const float* __restrict__ rois,
                                                      const unsigned* __restrict__ rank,
                                                      unsigned* __restrict__ order,
                                                      float4* __restrict__ sboxes) {
    const int i = blockIdx.x * 256 + threadIdx.x;
    const unsigned r = rank[i];
    order[r] = (unsigned)i;
    sboxes[r] = ((const float4*)rois)[i];
}

// ---------------- IoU (contraction-safe, matches numpy op order) ----------------
__device__ __forceinline__ bool iou_over(const float4 A, const float4 B) {
    float areaA = __fmul_rn(__fsub_rn(A.z, A.x), __fsub_rn(A.w, A.y));
    float areaB = __fmul_rn(__fsub_rn(B.z, B.x), __fsub_rn(B.w, B.y));
    float ix1 = fmaxf(A.x, B.x);
    float iy1 = fmaxf(A.y, B.y);
    float ix2 = fminf(A.z, B.z);
    float iy2 = fminf(A.w, B.w);
    float iw = fmaxf(__fsub_rn(ix2, ix1), 0.0f);
    float ih = fmaxf(__fsub_rn(iy2, iy1), 0.0f);
    float inter = __fmul_rn(iw, ih);
    float uni = __fsub_rn(__fadd_rn(areaA, areaB), inter);
    float iou = __fdiv_rn(inter, fmaxf(uni, 1e-9f));
    return iou > THR;
}

// ---------------- build sparse suppression structures (upper triangle, 1-D grid) ----------------
__global__ __launch_bounds__(256) void edge_kernel(const float4* __restrict__ sboxes,
                                                   unsigned long long* __restrict__ premask,
                                                   unsigned* __restrict__ cnt,
                                                   unsigned short* __restrict__ edges) {
    // decode block id -> (ti, tj) with ti <= tj < 128. cum(t) = 128t - t(t-1)/2
    const int k = blockIdx.x;
    int ti = (int)((257.0f - sqrtf(66049.0f - 8.0f * (float)k)) * 0.5f);
    if (ti > 127) ti = 127;
    if (ti < 0) ti = 0;
    while (ti < 127 && (128 * (ti + 1) - ((ti + 1) * ti) / 2) <= k) ++ti;
    while (ti > 0 && (128 * ti - (ti * (ti - 1)) / 2) > k) --ti;
    const int tj = ti + (k - (128 * ti - (ti * (ti - 1)) / 2));

    __shared__ float4 rb[64], cb[64];
    const int t = threadIdx.x;
    if (t < 64) rb[t] = sboxes[ti * 64 + t];
    else if (t < 128) cb[t - 64] = sboxes[tj * 64 + (t - 64)];
    __syncthreads();
    #pragma unroll
    for (int kk = 0; kk < 16; ++kk) {
        int p = kk * 256 + t;          // 0..4095
        int r = p >> 6, c = p & 63;
        int is = ti * 64 + r, js = tj * 64 + c;
        if (js <= is) continue;
        if (iou_over(rb[r], cb[c])) {
            if (ti == tj) {
                atomicOr(&premask[js], 1ull << r);
            } else {
                unsigned pos = atomicAdd(&cnt[is], 1u);
                if (pos < CAP) edges[is * CAP + pos] = (unsigned short)js;
            }
        }
    }
}

// ---------------- sequential greedy resolve: 1 wave, 128 chunks of 64 ----------------
// 8-deep register prefetch (premask, cnt, first 32 edges); ballot-fixpoint
// within-chunk resolve (no shfl); lgkmcnt-only ordering (no vmcnt drains).

#define PF(B, CH) do { \
    int ch_ = (CH); \
    if (ch_ < 128) { \
        int pb_ = ch_ * 64 + lane; \
        const unsigned short* er_ = edges + (size_t)pb_ * CAP; \
        pm##B  = premask[pb_]; \
        n##B   = cnt[pb_]; \
        e##B##a = *(const uint4*)(er_); \
        e##B##b = *(const uint4*)(er_ + 8); \
        e##B##c = *(const uint4*)(er_ + 16); \
        e##B##d = *(const uint4*)(er_ + 24); \
    } \
} while (0)

#define E1(i, W, SH) \
    if ((i) < nn_) { unsigned d_ = ((W) >> (SH)) & 0xFFFFu; atomicAnd(&alive[d_ >> 5], ~(1u << (d_ & 31))); }

#define STEP(B, C) do { \
    const unsigned av_ = (alive[(C) * 2 + (lane >> 5)] >> (lane & 31)) & 1u; \
    bool mydec = !av_ || (pm##B == 0ull); \
    unsigned long long decided = __ballot(mydec); \
    unsigned long long kept    = __ballot(av_ && (pm##B == 0ull)); \
    while (decided != ~0ull) { \
        bool ready = !mydec && ((pm##B & ~decided) == 0ull); \
        bool k_    = ready && ((pm##B & kept) == 0ull); \
        kept    |= __ballot(k_); \
        decided |= __ballot(ready); \
        mydec = mydec || ready; \
    } \
    unsigned nn_ = ((kept >> lane) & 1ull) ? (n##B > CAP ? CAP : n##B) : 0u; \
    if (__any(nn_ != 0u)) { \
        E1(0u,  e##B##a.x, 0) E1(1u,  e##B##a.x, 16) E1(2u,  e##B##a.y, 0) E1(3u,  e##B##a.y, 16) \
        E1(4u,  e##B##a.z, 0) E1(5u,  e##B##a.z, 16) E1(6u,  e##B##a.w, 0) E1(7u,  e##B##a.w, 16) \
        if (__any(nn_ > 8u)) { \
            E1(8u,  e##B##b.x, 0) E1(9u,  e##B##b.x, 16) E1(10u, e##B##b.y, 0) E1(11u, e##B##b.y, 16) \
            E1(12u, e##B##b.z, 0) E1(13u, e##B##b.z, 16) E1(14u, e##B##b.w, 0) E1(15u, e##B##b.w, 16) \
            if (__any(nn_ > 16u)) { \
                E1(16u, e##B##c.x, 0) E1(17u, e##B##c.x, 16) E1(18u, e##B##c.y, 0) E1(19u, e##B##c.y, 16) \
                E1(20u, e##B##c.z, 0) E1(21u, e##B##c.z, 16) E1(22u, e##B##c.w, 0) E1(23u, e##B##c.w, 16) \
                if (__any(nn_ > 24u)) { \
                    E1(24u, e##B##d.x, 0) E1(25u, e##B##d.x, 16) E1(26u, e##B##d.y, 0) E1(27u, e##B##d.y, 16) \
                    E1(28u, e##B##d.z, 0) E1(29u, e##B##d.z, 16) E1(30u, e##B##d.w, 0) E1(31u, e##B##d.w, 16) \
                    if (__any(nn_ > 32u)) { \
                        for (unsigned e2_ = 32; e2_ < nn_; ++e2_) { \
                            unsigned d_ = edges[(size_t)((C) * 64 + lane) * CAP + e2_]; \
                            atomicAnd(&alive[d_ >> 5], ~(1u << (d_ & 31))); \
                        } \
                    } \
                } \
            } \
        } \
    } \
    if (lane == 0) keptw[(C)] = kept; \
    PF(B, (C) + 8); \
    asm volatile("s_waitcnt lgkmcnt(0)" ::: "memory"); \
} while (0)

__global__ __launch_bounds__(64) void resolve_kernel(const unsigned long long* __restrict__ premask,
                                                     const unsigned* __restrict__ cnt,
                                                     const unsigned short* __restrict__ edges,
                                                     unsigned long long* __restrict__ keptw) {
    __shared__ unsigned alive[256];       // 8192-bit alive bitmap
    const int lane = threadIdx.x;
    #pragma unroll
    for (int w = 0; w < 4; ++w) alive[w * 64 + lane] = 0xFFFFFFFFu;
    asm volatile("s_waitcnt lgkmcnt(0)" ::: "memory");

    unsigned long long pm0, pm1, pm2, pm3, pm4, pm5, pm6, pm7;
    unsigned n0, n1, n2, n3, n4, n5, n6, n7;
    uint4 e0a, e0b, e0c, e0d, e1a, e1b, e1c, e1d, e2a, e2b, e2c, e2d, e3a, e3b, e3c, e3d;
    uint4 e4a, e4b, e4c, e4d, e5a, e5b, e5c, e5d, e6a, e6b, e6c, e6d, e7a, e7b, e7c, e7d;

    PF(0, 0); PF(1, 1); PF(2, 2); PF(3, 3);
    PF(4, 4); PF(5, 5); PF(6, 6); PF(7, 7);

    for (int cc = 0; cc < 128; cc += 8) {
        STEP(0, cc + 0); STEP(1, cc + 1); STEP(2, cc + 2); STEP(3, cc + 3);
        STEP(4, cc + 4); STEP(5, cc + 5); STEP(6, cc + 6); STEP(7, cc + 7);
    }
}

// ---------------- scatter output back through permutation ----------------
__global__ __launch_bounds__(256) void out_kernel(const float* __restrict__ scores,
                                                  const unsigned* __restrict__ order,
                                                  const unsigned long long* __restrict__ keptw,
                                                  float* __restrict__ out) {
    const int s = blockIdx.x * 256 + threadIdx.x;
    const unsigned orig = order[s];
    const unsigned keep = (unsigned)((keptw[s >> 6] >> (s & 63)) & 1ull);
    out[orig] = keep ? scores[orig] : 0.0f;
}

extern "C" void kernel_launch(void* const* d_in, const int* in_sizes, int n_in,
                              void* d_out, int out_size, void* d_ws, size_t ws_size,
                              hipStream_t stream) {
    const float* rois   = (const float*)d_in[0];
    const float* scores = (const float*)d_in[1];
    float* out = (float*)d_out;

    char* ws = (char*)d_ws;
    unsigned*            rank    = (unsigned*)(ws);                       // 32 KB
    unsigned*            cnt     = (unsigned*)(ws + 32768);               // 32 KB
    unsigned long long*  premask = (unsigned long long*)(ws + 65536);     // 64 KB
    unsigned*            order   = (unsigned*)(ws + 131072);              // 32 KB
    float4*              sboxes  = (float4*)(ws + 163840);                // 128 KB
    unsigned long long*  keptw   = (unsigned long long*)(ws + 294912);    // 1 KB
    unsigned short*      edges   = (unsigned short*)(ws + 295936);        // 1 MB

    // zero rank, cnt, premask (first 128 KB)
    hipMemsetAsync(ws, 0, 131072, stream);

    rank_kernel<<<dim3(32, 8), 256, 0, stream>>>(scores, rank);
    scatter_kernel<<<32, 256, 0, stream>>>(rois, rank, order, sboxes);
    edge_kernel<<<8256, 256, 0, stream>>>(sboxes, premask, cnt, edges);
    resolve_kernel<<<1, 64, 0, stream>>>(premask, cnt, edges, keptw);
    out_kernel<<<32, 256, 0, stream>>>(scores, order, keptw, out);
}

// Round 4
// 132.776 us; speedup vs baseline: 1.2992x; 1.2992x over previous
//
#include <hip/hip_runtime.h>

#define N 8192
#define CAP 64          // total out-edges per box stored (8 fast + 56 overflow)
#define THR 0.2f

// ---------------- rank: rank[i] = #{j: s_j > s_i or (s_j==s_i and j<i)} ----------------
__global__ __launch_bounds__(256) void rank_kernel(const float* __restrict__ scores,
                                                   unsigned* __restrict__ rank) {
    __shared__ float s[1024];
    const int jbase = blockIdx.y * 1024;
    for (int t = threadIdx.x; t < 1024; t += 256) s[t] = scores[jbase + t];
    __syncthreads();
    const int i = blockIdx.x * 256 + threadIdx.x;
    const float si = scores[i];
    unsigned c = 0;
    #pragma unroll 8
    for (int jj = 0; jj < 1024; ++jj) {
        float sj = s[jj];
        int j = jbase + jj;
        c += (sj > si) || (sj == si && j < i);
    }
    atomicAdd(&rank[i], c);
}

// ---------------- scatter into sorted order ----------------
__global__ __launch_bounds__(256) void scatter_kernel(const float* __restrict__ rois,
                                                      const unsigned* __restrict__ rank,
                                                      unsigned* __restrict__ order,
                                                      float4* __restrict__ sboxes) {
    const int i = blockIdx.x * 256 + threadIdx.x;
    const unsigned r = rank[i];
    order[r] = (unsigned)i;
    sboxes[r] = ((const float4*)rois)[i];
}

// ---------------- IoU (contraction-safe, matches numpy op order) ----------------
__device__ __forceinline__ bool iou_over(const float4 A, const float4 B) {
    float areaA = __fmul_rn(__fsub_rn(A.z, A.x), __fsub_rn(A.w, A.y));
    float areaB = __fmul_rn(__fsub_rn(B.z, B.x), __fsub_rn(B.w, B.y));
    float ix1 = fmaxf(A.x, B.x);
    float iy1 = fmaxf(A.y, B.y);
    float ix2 = fminf(A.z, B.z);
    float iy2 = fminf(A.w, B.w);
    float iw = fmaxf(__fsub_rn(ix2, ix1), 0.0f);
    float ih = fmaxf(__fsub_rn(iy2, iy1), 0.0f);
    float inter = __fmul_rn(iw, ih);
    float uni = __fsub_rn(__fadd_rn(areaA, areaB), inter);
    float iou = __fdiv_rn(inter, fmaxf(uni, 1e-9f));
    return iou > THR;
}

// ---------------- build sparse suppression structures (upper triangle, 1-D grid) ----------------
// edgesTS: transposed fast-path edges. Slot p (p<8) of box is lives at
//   u16 index (((is>>6)*2 + (p>>2))*64 + (is&63))*4 + (p&3)
// so resolve's per-(chunk,slotgrp) u64 loads are lane-coalesced.
__global__ __launch_bounds__(256) void edge_kernel(const float4* __restrict__ sboxes,
                                                   unsigned long long* __restrict__ premask,
                                                   unsigned* __restrict__ cnt,
                                                   unsigned short* __restrict__ edgesTS,
                                                   unsigned short* __restrict__ edgesOvf) {
    // decode block id -> (ti, tj) with ti <= tj < 128
    const int k = blockIdx.x;
    int ti = (int)((257.0f - sqrtf(66049.0f - 8.0f * (float)k)) * 0.5f);
    if (ti > 127) ti = 127;
    if (ti < 0) ti = 0;
    while (ti < 127 && (128 * (ti + 1) - ((ti + 1) * ti) / 2) <= k) ++ti;
    while (ti > 0 && (128 * ti - (ti * (ti - 1)) / 2) > k) --ti;
    const int tj = ti + (k - (128 * ti - (ti * (ti - 1)) / 2));

    __shared__ float4 rb[64], cb[64];
    const int t = threadIdx.x;
    if (t < 64) rb[t] = sboxes[ti * 64 + t];
    else if (t < 128) cb[t - 64] = sboxes[tj * 64 + (t - 64)];
    __syncthreads();
    #pragma unroll
    for (int kk = 0; kk < 16; ++kk) {
        int p = kk * 256 + t;          // 0..4095
        int r = p >> 6, c = p & 63;
        int is = ti * 64 + r, js = tj * 64 + c;
        if (js <= is) continue;
        if (iou_over(rb[r], cb[c])) {
            if (ti == tj) {
                atomicOr(&premask[js], 1ull << r);
            } else {
                unsigned pos = atomicAdd(&cnt[is], 1u);
                if (pos < 8) {
                    edgesTS[(((is >> 6) * 2 + (pos >> 2)) * 64 + (is & 63)) * 4 + (pos & 3)] =
                        (unsigned short)js;
                } else if (pos < CAP) {
                    edgesOvf[(size_t)is * 56 + (pos - 8)] = (unsigned short)js;
                }
            }
        }
    }
}

// ---------------- sequential greedy resolve: 1 wave, 128 chunks of 64 ----------------
// 8-deep coalesced register prefetch; branchless masked LDS atomics in the
// common path; rare scalar-branch-gated fixpoint / overflow.

#define PF(B, CH) do { \
    int ch_ = (CH); \
    if (ch_ < 128) { \
        int pb_ = ch_ * 64 + lane; \
        pm##B = premask[pb_]; \
        n##B  = cnt[pb_]; \
        ea##B = edgesT[(ch_ * 2 + 0) * 64 + lane]; \
        eb##B = edgesT[(ch_ * 2 + 1) * 64 + lane]; \
    } \
} while (0)

// one unconditional masked atomic: invalid slots AND with ~0 at a bank-spread dummy word
#define APPLY(i, W, SH) { \
    unsigned d_ = (unsigned)((W) >> (SH)) & 0xFFFFu; \
    bool v_ = (i) < nn_; \
    unsigned a_ = v_ ? (d_ >> 5) : (unsigned)lane; \
    unsigned m_ = v_ ? ~(1u << (d_ & 31)) : ~0u; \
    atomicAnd(&alive[a_], m_); }

#define STEP(B, C) do { \
    const unsigned av_ = (alive[(C) * 2 + (lane >> 5)] >> (lane & 31)) & 1u; \
    unsigned long long anz = __ballot(pm##B != 0ull); \
    unsigned long long kept = __ballot(av_ != 0u); \
    if (anz != 0ull) { \
        bool mydec = !av_ || (pm##B == 0ull); \
        unsigned long long decided = __ballot(mydec); \
        kept = __ballot(av_ && (pm##B == 0ull)); \
        while (decided != ~0ull) { \
            bool ready = !mydec && ((pm##B & ~decided) == 0ull); \
            bool k_ = ready && ((pm##B & kept) == 0ull); \
            kept |= __ballot(k_); \
            decided |= __ballot(ready); \
            mydec = mydec || ready; \
        } \
    } \
    if (lane == 0) keptw[(C)] = kept; \
    const unsigned kb_ = (unsigned)(kept >> lane) & 1u; \
    unsigned nn_ = kb_ ? (n##B > 8u ? 8u : n##B) : 0u; \
    APPLY(0u, ea##B, 0)  APPLY(1u, ea##B, 16) APPLY(2u, ea##B, 32) APPLY(3u, ea##B, 48) \
    APPLY(4u, eb##B, 0)  APPLY(5u, eb##B, 16) APPLY(6u, eb##B, 32) APPLY(7u, eb##B, 48) \
    if (__any(kb_ && n##B > 8u)) { \
        unsigned nf_ = kb_ ? (n##B > CAP ? (unsigned)CAP : n##B) : 0u; \
        for (unsigned e_ = 8; e_ < nf_; ++e_) { \
            unsigned d_ = edgesOvf[(size_t)((C) * 64 + lane) * 56 + (e_ - 8)]; \
            atomicAnd(&alive[d_ >> 5], ~(1u << (d_ & 31))); \
        } \
    } \
    PF(B, (C) + 8); \
    asm volatile("s_waitcnt lgkmcnt(0)" ::: "memory"); \
} while (0)

__global__ __launch_bounds__(64) void resolve_kernel(const unsigned long long* __restrict__ premask,
                                                     const unsigned* __restrict__ cnt,
                                                     const unsigned long long* __restrict__ edgesT,
                                                     const unsigned short* __restrict__ edgesOvf,
                                                     unsigned long long* __restrict__ keptw) {
    __shared__ unsigned alive[256];       // 8192-bit alive bitmap
    const int lane = threadIdx.x;
    #pragma unroll
    for (int w = 0; w < 4; ++w) alive[w * 64 + lane] = 0xFFFFFFFFu;
    asm volatile("s_waitcnt lgkmcnt(0)" ::: "memory");

    unsigned long long pm0, pm1, pm2, pm3, pm4, pm5, pm6, pm7;
    unsigned n0, n1, n2, n3, n4, n5, n6, n7;
    unsigned long long ea0, ea1, ea2, ea3, ea4, ea5, ea6, ea7;
    unsigned long long eb0, eb1, eb2, eb3, eb4, eb5, eb6, eb7;

    PF(0, 0); PF(1, 1); PF(2, 2); PF(3, 3);
    PF(4, 4); PF(5, 5); PF(6, 6); PF(7, 7);

    for (int cc = 0; cc < 128; cc += 8) {
        STEP(0, cc + 0); STEP(1, cc + 1); STEP(2, cc + 2); STEP(3, cc + 3);
        STEP(4, cc + 4); STEP(5, cc + 5); STEP(6, cc + 6); STEP(7, cc + 7);
    }
}

// ---------------- scatter output back through permutation ----------------
__global__ __launch_bounds__(256) void out_kernel(const float* __restrict__ scores,
                                                  const unsigned* __restrict__ order,
                                                  const unsigned long long* __restrict__ keptw,
                                                  float* __restrict__ out) {
    const int s = blockIdx.x * 256 + threadIdx.x;
    const unsigned orig = order[s];
    const unsigned keep = (unsigned)((keptw[s >> 6] >> (s & 63)) & 1ull);
    out[orig] = keep ? scores[orig] : 0.0f;
}

extern "C" void kernel_launch(void* const* d_in, const int* in_sizes, int n_in,
                              void* d_out, int out_size, void* d_ws, size_t ws_size,
                              hipStream_t stream) {
    const float* rois   = (const float*)d_in[0];
    const float* scores = (const float*)d_in[1];
    float* out = (float*)d_out;

    char* ws = (char*)d_ws;
    unsigned*            rank     = (unsigned*)(ws);                       // 32 KB
    unsigned*            cnt      = (unsigned*)(ws + 32768);               // 32 KB
    unsigned long long*  premask  = (unsigned long long*)(ws + 65536);     // 64 KB
    unsigned*            order    = (unsigned*)(ws + 131072);              // 32 KB
    float4*              sboxes   = (float4*)(ws + 163840);                // 128 KB
    unsigned long long*  keptw    = (unsigned long long*)(ws + 294912);    // 1 KB
    unsigned long long*  edgesT   = (unsigned long long*)(ws + 295936);    // 128 KB
    unsigned short*      edgesOvf = (unsigned short*)(ws + 427008);        // 896 KB

    // zero rank, cnt, premask (first 128 KB)
    hipMemsetAsync(ws, 0, 131072, stream);

    rank_kernel<<<dim3(32, 8), 256, 0, stream>>>(scores, rank);
    scatter_kernel<<<32, 256, 0, stream>>>(rois, rank, order, sboxes);
    edge_kernel<<<8256, 256, 0, stream>>>(sboxes, premask, cnt,
                                          (unsigned short*)edgesT, edgesOvf);
    resolve_kernel<<<1, 64, 0, stream>>>(premask, cnt, edgesT, edgesOvf, keptw);
    out_kernel<<<32, 256, 0, stream>>>(scores, order, keptw, out);
}